// Round 5
// baseline (125.428 us; speedup 1.0000x reference)
//
#include <hip/hip_runtime.h>

// DelayedXOR SH-SNN forward. Chains (b,h) are fully independent
// (s_g.reshape(B,H) maps (g,j)->h=g*16+j one-to-one).
//
// R4 -> R5: with x staged in LDS, snn dropped 52->~40us but remains ~95
// cyc/step vs a ~30 cyc/step issue floor -> single-wave in-order dependency
// latency (the per-step chain is ~10 back-to-back dependent VALU ops; no TLP
// at 1 wave/SIMD). Fix: TWO independent chains per thread, source-interleaved
// so consecutive instructions alternate chains (A,B,A,B...) giving ~4 cyc of
// natural spacing between dependent ops. Waves halve to 256 (1/CU); issue
// cost/step doubles to ~64 cyc but replaces ~95 cyc of exposed latency.
//
// Correctness: bit-exact fp32 vs numpy reference (absmax 0.0 in R1-R4).
// - fp contract OFF everywhere (no fma fusion)
// - exact expression order ((ag*v + omg*gi) - sf)
// - spike(v-1) == (v > 1.0f) exactly in fp32
// - (1-alpha)*integ as sf*oms: exact since sf in {0,1}
// - sigmoid in double, rounded once to fp32

constexpr int T     = 1024;
constexpr int H     = 32;
// decision_start = max(T - T/4, T/2) = 768 -> tile 48 of 64 (16 steps/tile)
constexpr int NTILE    = 64;
constexpr int ACC_TILE = 48;

struct XT { float4 q0, q1, q2, q3, q4, q5, q6, q7; };  // 16 timesteps

__device__ __forceinline__ XT lds_tile(const float4* s, int k)
{
    int i = k * 8;
    XT t;
    t.q0 = s[i+0]; t.q1 = s[i+1]; t.q2 = s[i+2]; t.q3 = s[i+3];
    t.q4 = s[i+4]; t.q5 = s[i+5]; t.q6 = s[i+6]; t.q7 = s[i+7];
    return t;
}

// One timestep for TWO independent chains, hand-interleaved A/B.
template <bool ACC>
__device__ __forceinline__ void step2(float xA0, float xA1, float xB0, float xB1,
                                      float w0, float w1,
                                      float ag, float omg, float as, float oms,
                                      float& vA, float& sfA, float& VA, float& SfA, float& accA,
                                      float& vB, float& sfB, float& VB, float& SfB, float& accB)
{
#pragma clang fp contract(off)
    float mA0 = xA0 * w0;           float mB0 = xB0 * w0;
    float mA1 = xA1 * w1;           float mB1 = xB1 * w1;
    float giA = mA0 + mA1;          float giB = mB0 + mB1;
    float t2A = omg * giA;          float t2B = omg * giB;
    float t1A = ag * vA;            float t1B = ag * vB;
    float uA  = t1A + t2A;          float uB  = t1B + t2B;
    vA = uA - sfA;                  vB = uB - sfB;
    sfA = (vA > 1.0f) ? 1.0f : 0.0f;  sfB = (vB > 1.0f) ? 1.0f : 0.0f;
    float a2A = sfA * oms;          float a2B = sfB * oms;
    float a1A = as * VA;            float a1B = as * VB;
    float a3A = a1A + a2A;          float a3B = a1B + a2B;
    VA = a3A - SfA;                 VB = a3B - SfB;
    SfA = (VA > 1.0f) ? 1.0f : 0.0f;  SfB = (VB > 1.0f) ? 1.0f : 0.0f;
    if (ACC) { accA += SfA;         accB += SfB; }
}

template <bool ACC>
__device__ __forceinline__ void tile16_2(const XT& tA, const XT& tB,
                                         float w0, float w1,
                                         float ag, float omg, float as, float oms,
                                         float& vA, float& sfA, float& VA, float& SfA, float& accA,
                                         float& vB, float& sfB, float& VB, float& SfB, float& accB)
{
#define STEP2Q(QA, QB) \
    step2<ACC>(QA.x, QA.y, QB.x, QB.y, w0, w1, ag, omg, as, oms, \
               vA, sfA, VA, SfA, accA, vB, sfB, VB, SfB, accB);  \
    step2<ACC>(QA.z, QA.w, QB.z, QB.w, w0, w1, ag, omg, as, oms, \
               vA, sfA, VA, SfA, accA, vB, sfB, VB, SfB, accB);
    STEP2Q(tA.q0, tB.q0) STEP2Q(tA.q1, tB.q1) STEP2Q(tA.q2, tB.q2) STEP2Q(tA.q3, tB.q3)
    STEP2Q(tA.q4, tB.q4) STEP2Q(tA.q5, tB.q5) STEP2Q(tA.q6, tB.q6) STEP2Q(tA.q7, tB.q7)
#undef STEP2Q
}

__global__ __launch_bounds__(64, 1) void snn_fwd(
    const float* __restrict__ x,       // [B, T, 2]
    const float* __restrict__ Wg,      // [2, 16, 2] == [h][2]
    const float* __restrict__ tau_m,   // [2, 16] == [h]
    const float* __restrict__ soma,    // [32]
    const float* __restrict__ W_out,   // [1, 32]
    const float* __restrict__ b_out,   // [1]
    float* __restrict__ out)           // [B, 1]
{
#pragma clang fp contract(off)
    // 4 batch rows per block (32 KB). Row r occupies sx[r*512 .. r*512+511].
    // Lanes 0-31: rows 0,1 (batches 4i, 4i+1); lanes 32-63: rows 2,3.
    __shared__ float4 sx[2048];

    const int tid  = threadIdx.x;
    const int h    = tid & (H - 1);
    const int half = tid >> 5;

    // Cooperative coalesced preload: all 4 rows contiguous in x.
    const float4* gx = (const float4*)x + (size_t)blockIdx.x * 2048;
#pragma unroll
    for (int k = 0; k < 32; ++k)
        sx[k * 64 + tid] = gx[k * 64 + tid];

    const float w0 = Wg[2*h + 0];
    const float w1 = Wg[2*h + 1];
    const float ag  = (float)(1.0 / (1.0 + exp(-(double)tau_m[h])));
    const float omg = 1.0f - ag;
    const float as  = (float)(1.0 / (1.0 + exp(-(double)soma[h])));
    const float oms = 1.0f - as;

    __syncthreads();

    const float4* sA = sx + (half * 2 + 0) * 512;   // chain A's row
    const float4* sB = sx + (half * 2 + 1) * 512;   // chain B's row

    float vA = 0.f, sfA = 0.f, VA = 0.f, SfA = 0.f, accA = 0.f;
    float vB = 0.f, sfB = 0.f, VB = 0.f, SfB = 0.f, accB = 0.f;

    XT curA = lds_tile(sA, 0);
    XT curB = lds_tile(sB, 0);

    // phase 1: tiles 0..47, no accumulation
    for (int k = 0; k < ACC_TILE; ++k) {
        XT nxtA = lds_tile(sA, k + 1);
        XT nxtB = lds_tile(sB, k + 1);
        tile16_2<false>(curA, curB, w0, w1, ag, omg, as, oms,
                        vA, sfA, VA, SfA, accA, vB, sfB, VB, SfB, accB);
        curA = nxtA; curB = nxtB;
    }
    // phase 2: tiles 48..62, accumulate S
    for (int k = ACC_TILE; k < NTILE - 1; ++k) {
        XT nxtA = lds_tile(sA, k + 1);
        XT nxtB = lds_tile(sB, k + 1);
        tile16_2<true>(curA, curB, w0, w1, ag, omg, as, oms,
                       vA, sfA, VA, SfA, accA, vB, sfB, VB, SfB, accB);
        curA = nxtA; curB = nxtB;
    }
    // tile 63
    tile16_2<true>(curA, curB, w0, w1, ag, omg, as, oms,
                   vA, sfA, VA, SfA, accA, vB, sfB, VB, SfB, accB);

    // out = sum_h acc[h]*W_out[h] + b_out, per chain. xor-reduce stays within
    // each 32-lane half for m <= 16.
    float valA = accA * W_out[h];
    float valB = accB * W_out[h];
#pragma unroll
    for (int m = 16; m >= 1; m >>= 1) {
        valA += __shfl_xor(valA, m, 64);
        valB += __shfl_xor(valB, m, 64);
    }
    if ((tid & 31) == 0) {
        const int ob = blockIdx.x * 4 + half * 2;
        out[ob + 0] = valA + b_out[0];
        out[ob + 1] = valB + b_out[0];
    }
}

extern "C" void kernel_launch(void* const* d_in, const int* in_sizes, int n_in,
                              void* d_out, int out_size, void* d_ws, size_t ws_size,
                              hipStream_t stream)
{
    const float* x     = (const float*)d_in[0];
    const float* Wg    = (const float*)d_in[1];
    const float* tau_m = (const float*)d_in[2];
    const float* soma  = (const float*)d_in[3];
    const float* W_out = (const float*)d_in[4];
    const float* b_out = (const float*)d_in[5];
    float* out = (float*)d_out;

    // 256 blocks x 64 threads; each thread runs 2 chains (batches 4i+2h+{0,1}),
    // each block covers batches [4i, 4i+4).
    dim3 grid(256), block(64);
    hipLaunchKernelGGL(snn_fwd, grid, block, 0, stream,
                       x, Wg, tau_m, soma, W_out, b_out, out);
}

// Round 6
// 94.788 us; speedup vs baseline: 1.3232x; 1.3232x over previous
//
#include <hip/hip_runtime.h>

// DelayedXOR SH-SNN forward. Chains (b,h) fully independent
// (s_g.reshape(B,H) maps (g,j)->h=g*16+j one-to-one).
//
// R5 -> R6: all waves are co-resident, so wall = per-wave serial time; R5's
// 2-chains/wave was a losing trade (76 vs 94 cyc/chain-step, x2 work). The
// un-hideable stall is the spike: v_cmp->v_cndmask through VCC (single arch
// register; serializes + wait-states, 2x per step). Replace with branchless
// plain-VALU spike:  s = med3(ceil(v-1), 0, 1)
// Exact: v>1 -> v-1 exactly positive (Sterbenz on [1,2], monotone RN above)
// -> ceil>=1 -> 1; v<=1 -> v-1<=0 -> ceil<=0 -> 0 (a -0 only propagates as
// sign-of-zero, which cannot flip any '>' or change any sum). Also hoist the
// state-independent drive e_t = omg*(x0*w0 + x1*w1) into a per-tile parallel
// precompute (same ops, same order) to feed the scheduler independent work.
// Back to 1 chain/thread (512 waves), R4's LDS staging kept.
//
// Correctness: bit-exact fp32 vs numpy reference (absmax 0.0 in R1-R5).
// - fp contract OFF everywhere (no fma fusion)
// - exact expression order ((ag*v + e) - sf)
// - (1-alpha)*integ as sf*oms: exact since sf in {0,1}
// - sigmoid in double, rounded once to fp32

constexpr int T     = 1024;
constexpr int H     = 32;
// decision_start = max(T - T/4, T/2) = 768 -> tile 48 of 64 (16 steps/tile)

__device__ __forceinline__ void make_e(const float4* s, int k, float (&e)[16],
                                       float w0, float w1, float omg)
{
#pragma clang fp contract(off)
#pragma unroll
    for (int i = 0; i < 8; ++i) {
        float4 q = s[k * 8 + i];
        e[2*i + 0] = omg * ((q.x * w0) + (q.y * w1));
        e[2*i + 1] = omg * ((q.z * w0) + (q.w * w1));
    }
}

template <bool ACC>
__device__ __forceinline__ void steps16(const float (&e)[16],
                                        float ag, float as, float oms,
                                        float& v, float& sf,
                                        float& V, float& Sf, float& acc)
{
#pragma clang fp contract(off)
#pragma unroll
    for (int i = 0; i < 16; ++i) {
        float t1 = ag * v;       // serial core: mul -> add -> sub (12 cyc)
        float u  = t1 + e[i];
        v = u - sf;
        // branchless spike, no VCC: sub, ceil, med3 (all plain VALU)
        sf = __builtin_amdgcn_fmed3f(__builtin_ceilf(v - 1.0f), 0.0f, 1.0f);
        float a1 = as * V;
        float a2 = sf * oms;     // exact for sf in {0,1}
        float a3 = a1 + a2;
        V = a3 - Sf;
        Sf = __builtin_amdgcn_fmed3f(__builtin_ceilf(V - 1.0f), 0.0f, 1.0f);
        if (ACC) acc += Sf;
    }
}

__global__ __launch_bounds__(64, 1) void snn_fwd(
    const float* __restrict__ x,       // [B, T, 2]
    const float* __restrict__ Wg,      // [2, 16, 2] == [h][2]
    const float* __restrict__ tau_m,   // [2, 16] == [h]
    const float* __restrict__ soma,    // [32]
    const float* __restrict__ W_out,   // [1, 32]
    const float* __restrict__ b_out,   // [1]
    float* __restrict__ out)           // [B, 1]
{
#pragma clang fp contract(off)
    // Two x rows per block (16 KB). Lanes 0-31: b=2*blk (sx[0..511]),
    // lanes 32-63: b=2*blk+1 (sx[512..1023]).
    __shared__ float4 sx[1024];

    const int tid  = threadIdx.x;
    const int h    = tid & (H - 1);
    const int half = tid >> 5;
    const int b    = (blockIdx.x << 1) | half;

    // Cooperative coalesced preload: both rows contiguous in x.
    const float4* gx = (const float4*)(x + (size_t)blockIdx.x * 4096);
#pragma unroll
    for (int k = 0; k < 16; ++k)
        sx[k * 64 + tid] = gx[k * 64 + tid];

    const float w0 = Wg[2*h + 0];
    const float w1 = Wg[2*h + 1];
    const float ag  = (float)(1.0 / (1.0 + exp(-(double)tau_m[h])));
    const float omg = 1.0f - ag;
    const float as  = (float)(1.0 / (1.0 + exp(-(double)soma[h])));
    const float oms = 1.0f - as;

    __syncthreads();

    const float4* sbase = sx + half * 512;   // this thread's row

    float v = 0.f, sf = 0.f, V = 0.f, Sf = 0.f, acc = 0.f;

    // Ping-pong e-buffers: precompute drive for tile k+1 while stepping tile k.
    float eA[16], eB[16];
    make_e(sbase, 0, eA, w0, w1, omg);

    // phase 1: tiles 0..47 (pairs), no accumulation; k=46 prefetches tile 48.
    for (int k = 0; k < 48; k += 2) {
        make_e(sbase, k + 1, eB, w0, w1, omg);
        steps16<false>(eA, ag, as, oms, v, sf, V, Sf, acc);
        make_e(sbase, k + 2, eA, w0, w1, omg);
        steps16<false>(eB, ag, as, oms, v, sf, V, Sf, acc);
    }
    // phase 2: tiles 48..61 (pairs), accumulate S; prefetch stays <= 62.
    for (int k = 48; k < 62; k += 2) {
        make_e(sbase, k + 1, eB, w0, w1, omg);
        steps16<true>(eA, ag, as, oms, v, sf, V, Sf, acc);
        make_e(sbase, k + 2, eA, w0, w1, omg);
        steps16<true>(eB, ag, as, oms, v, sf, V, Sf, acc);
    }
    // tail: tiles 62 (in eA) and 63
    make_e(sbase, 63, eB, w0, w1, omg);
    steps16<true>(eA, ag, as, oms, v, sf, V, Sf, acc);
    steps16<true>(eB, ag, as, oms, v, sf, V, Sf, acc);

    // out[b] = sum_h acc[h] * W_out[h] + b_out; xor-reduce stays within each
    // 32-lane half for m <= 16.
    float val = acc * W_out[h];
#pragma unroll
    for (int m = 16; m >= 1; m >>= 1)
        val += __shfl_xor(val, m, 64);
    if ((tid & 31) == 0)
        out[b] = val + b_out[0];
}

extern "C" void kernel_launch(void* const* d_in, const int* in_sizes, int n_in,
                              void* d_out, int out_size, void* d_ws, size_t ws_size,
                              hipStream_t stream)
{
    const float* x     = (const float*)d_in[0];
    const float* Wg    = (const float*)d_in[1];
    const float* tau_m = (const float*)d_in[2];
    const float* soma  = (const float*)d_in[3];
    const float* W_out = (const float*)d_in[4];
    const float* b_out = (const float*)d_in[5];
    float* out = (float*)d_out;

    // 512 blocks x 64 threads = one (b,h) chain per thread.
    dim3 grid(512), block(64);
    hipLaunchKernelGGL(snn_fwd, grid, block, 0, stream,
                       x, Wg, tau_m, soma, W_out, b_out, out);
}